// Round 3
// baseline (738.478 us; speedup 1.0000x reference)
//
#include <hip/hip_runtime.h>

// NaN-aware conv2d. FP32 I/O (per reference setup_inputs), bf16 MFMA compute.
// x[16,128,128,128] NCHW f32, kernel[256,128,3,3] OIHW f32, bias[256] f32
// -> out[16,256,128,128] f32.  STRIDE=1 PAD=1 THRESHOLD=0.5 (never fires at 5% NaN).
//
// out = conv(nan_to_zero(x),K) + patch_mean*conv(isnan(x),K) + bias
//     = conv(A~,K) + bias,  A~ = x with NaN -> patch_mean of destination patch.
// Single implicit GEMM: M=262144 (b,oh,ow), N=256 (oc), K=1152 (c,kh,kw).

typedef __attribute__((ext_vector_type(8))) short bf16x8;
typedef __attribute__((ext_vector_type(4))) float f32x4;

#define HH 128
#define WW 128
#define CC 128

__device__ __forceinline__ unsigned short f2bf(float f) {
    union { float f; unsigned int i; } v; v.f = f;
    unsigned int u = v.i;
    if ((u & 0x7FFFFFFFu) > 0x7F800000u) return (unsigned short)((u >> 16) | 0x0040u);
    unsigned int r = u + 0x7FFFu + ((u >> 16) & 1u);  // RNE
    return (unsigned short)(r >> 16);
}
__device__ __forceinline__ unsigned int sel2(unsigned int v, unsigned int pmu) {
    // per-16-bit bf16 lane: isnan ? pm : value
    unsigned int lo = v & 0xFFFFu, hi = v >> 16;
    if ((lo & 0x7FFFu) > 0x7F80u) lo = pmu;
    if ((hi & 0x7FFFu) > 0x7F80u) hi = pmu;
    return lo | (hi << 16);
}

// ---- kernel 1: NCHW f32 -> NHWC bf16 (group-local) + per-pixel channel NaN stats --
__global__ void k_transpose_stats(const float* __restrict__ x,
                                  unsigned short* __restrict__ xT,
                                  float* __restrict__ cnt,
                                  float* __restrict__ sum, int b0) {
    int bh = blockIdx.x;              // bl*128 + h
    int bl = bh >> 7, h = bh & 127;
    int b = b0 + bl;
    int w = threadIdx.x;              // 0..127
    const float* xp = x + ((long)b * CC * HH * WW) + h * WW + w;
    unsigned short* xTp = xT + ((((long)bh << 7) + w) << 7);
    int cntv = 0; float sumv = 0.f;
    for (int c8 = 0; c8 < 16; ++c8) {
        unsigned short s8[8];
        #pragma unroll
        for (int j = 0; j < 8; ++j) {
            float fv = xp[(long)(c8 * 8 + j) * (HH * WW)];
            unsigned int bits = __float_as_uint(fv);
            if ((bits & 0x7FFFFFFFu) > 0x7F800000u) { cntv++; s8[j] = 0x7FC0u; }
            else { sumv += fv; s8[j] = f2bf(fv); }
        }
        uint4 p;
        p.x = (unsigned)s8[0] | ((unsigned)s8[1] << 16);
        p.y = (unsigned)s8[2] | ((unsigned)s8[3] << 16);
        p.z = (unsigned)s8[4] | ((unsigned)s8[5] << 16);
        p.w = (unsigned)s8[6] | ((unsigned)s8[7] << 16);
        *(uint4*)(xTp + c8 * 8) = p;
    }
    cnt[(bh << 7) + w] = (float)cntv;
    sum[(bh << 7) + w] = sumv;
}

// ---- kernel 2: 3x3 window of per-pixel stats -> patch_mean bf16 -------------------
__global__ void k_patchmean(const float* __restrict__ cnt, const float* __restrict__ sum,
                            unsigned short* __restrict__ pm) {
    int idx = blockIdx.x * 256 + threadIdx.x;     // (bl*128+oh)*128+ow
    int ow = idx & 127, oh = (idx >> 7) & 127, bl = idx >> 14;
    float nc = 0.f, vs = 0.f;
    #pragma unroll
    for (int kh = 0; kh < 3; ++kh) {
        int ih = oh + kh - 1; if (ih < 0 || ih >= HH) continue;
        #pragma unroll
        for (int kw = 0; kw < 3; ++kw) {
            int iw = ow + kw - 1; if (iw < 0 || iw >= WW) continue;
            int p = (((bl << 7) + ih) << 7) + iw;
            nc += cnt[p]; vs += sum[p];
        }
    }
    float pmv = vs / fmaxf(1152.f - nc, 1.f);
    unsigned short r = f2bf(pmv);
    if (nc >= 576.f) r = 0x7FC0u;                 // bad patch (statistically impossible here)
    pm[idx] = r;
}

// ---- kernel 3: kernel f32 OIHW -> W2 bf16 [khw][oc][c] ----------------------------
__global__ void k_w2(const float* __restrict__ krn, unsigned short* __restrict__ W2) {
    int e = blockIdx.x * 256 + threadIdx.x;       // (khw*256+oc)*128+c ; 294912
    int c = e & 127, oc = (e >> 7) & 255, khw = e >> 15;
    W2[e] = f2bf(krn[(oc * 128 + c) * 9 + khw]);
}

// ---- kernel 4: implicit-GEMM MFMA conv, fp32 epilogue -----------------------------
// block 256 = 4 waves (2x2), tile 128 pixels x 128 oc, wave 64x64 = 4x4 of 16x16x32.
__global__ __launch_bounds__(256) void k_gemm(
    const unsigned short* __restrict__ xT, const unsigned short* __restrict__ pm,
    const unsigned short* __restrict__ W2, const float* __restrict__ bias,
    float* __restrict__ out, int b0) {
    __shared__ __align__(16) unsigned short lA[128 * 72];
    __shared__ __align__(16) unsigned short lB[128 * 72];
    int bid = blockIdx.x;
    int nt = bid & 1;                 // oc half
    int mtl = bid >> 1;               // local m-tile = bl*128 + oh
    int bl = mtl >> 7, oh = mtl & 127;
    int b = b0 + bl;
    int oc0 = nt << 7;
    int tid = threadIdx.x;
    int lane = tid & 63, wave = tid >> 6;
    int wm = wave >> 1, wn = wave & 1;
    int l15 = lane & 15, quad = lane >> 4;

    int sr = tid >> 1;                // staged row (= ow / oc row)
    int sc = (tid & 1) * 32;          // 32-short half of the 64-wide K-slab
    unsigned int pmr = pm[(mtl << 7) + sr];

    f32x4 acc[4][4];
    #pragma unroll
    for (int i = 0; i < 4; ++i)
        #pragma unroll
        for (int j = 0; j < 4; ++j) acc[i][j] = (f32x4)0.f;

    for (int kh = 0; kh < 3; ++kh) {
        int ih = oh + kh - 1;
        if (ih < 0 || ih >= HH) continue;         // block-uniform
        for (int kw = 0; kw < 3; ++kw) {
            int iw = sr + kw - 1;
            bool inb = (iw >= 0 && iw < WW);
            const unsigned short* ap = xT + (((((bl << 7) + ih) << 7) + iw) << 7) + sc;
            int khw = kh * 3 + kw;
            const unsigned short* bp = W2 + (((khw << 8) + oc0 + sr) << 7) + sc;
            for (int c0 = 0; c0 < 128; c0 += 64) {
                __syncthreads();
                unsigned short* la = &lA[sr * 72 + sc];
                if (inb) {
                    #pragma unroll
                    for (int i = 0; i < 4; ++i) {
                        uint4 v = *(const uint4*)(ap + c0 + i * 8);
                        uint4 r;
                        r.x = sel2(v.x, pmr); r.y = sel2(v.y, pmr);
                        r.z = sel2(v.z, pmr); r.w = sel2(v.w, pmr);
                        *(uint4*)(la + i * 8) = r;
                    }
                } else {
                    uint4 z; z.x = 0; z.y = 0; z.z = 0; z.w = 0;
                    #pragma unroll
                    for (int i = 0; i < 4; ++i) *(uint4*)(la + i * 8) = z;
                }
                unsigned short* lb = &lB[sr * 72 + sc];
                #pragma unroll
                for (int i = 0; i < 4; ++i)
                    *(uint4*)(lb + i * 8) = *(const uint4*)(bp + c0 + i * 8);
                __syncthreads();
                #pragma unroll
                for (int ks = 0; ks < 2; ++ks) {
                    bf16x8 af[4], bfr[4];
                    #pragma unroll
                    for (int mi = 0; mi < 4; ++mi)
                        af[mi] = *(const bf16x8*)&lA[((wm << 6) + (mi << 4) + l15) * 72 + (ks << 5) + (quad << 3)];
                    #pragma unroll
                    for (int ni = 0; ni < 4; ++ni)
                        bfr[ni] = *(const bf16x8*)&lB[((wn << 6) + (ni << 4) + l15) * 72 + (ks << 5) + (quad << 3)];
                    #pragma unroll
                    for (int mi = 0; mi < 4; ++mi)
                        #pragma unroll
                        for (int ni = 0; ni < 4; ++ni)
                            acc[mi][ni] = __builtin_amdgcn_mfma_f32_16x16x32_bf16(
                                af[mi], bfr[ni], acc[mi][ni], 0, 0, 0);
                }
            }
        }
    }

    // epilogue: C/D layout col(n)=lane&15 -> oc, row(m)=quad*4+reg -> ow. fp32 out.
    #pragma unroll
    for (int ni = 0; ni < 4; ++ni) {
        int oc = oc0 + (wn << 6) + (ni << 4) + l15;
        float bv = bias[oc];
        float* op = out + ((long)((b << 8) + oc) * 128 + oh) * 128;
        #pragma unroll
        for (int mi = 0; mi < 4; ++mi) {
            int ow0 = (wm << 6) + (mi << 4) + (quad << 2);
            float4 o;
            o.x = acc[mi][ni][0] + bv;
            o.y = acc[mi][ni][1] + bv;
            o.z = acc[mi][ni][2] + bv;
            o.w = acc[mi][ni][3] + bv;
            *(float4*)(op + ow0) = o;
        }
    }
}

extern "C" void kernel_launch(void* const* d_in, const int* in_sizes, int n_in,
                              void* d_out, int out_size, void* d_ws, size_t ws_size,
                              hipStream_t stream) {
    const float* x    = (const float*)d_in[0];
    const float* krn  = (const float*)d_in[1];
    const float* bias = (const float*)d_in[2];
    float* out = (float*)d_out;

    // pick batch-group size G so scratch fits ws_size
    const size_t W2_BYTES = 294912ull * 2;                 // 576 KB bf16
    int G = 16;
    while (G > 1) {
        size_t need = W2_BYTES + 256
                    + (size_t)G * (16384ull * 128 * 2)      // xT: G*4MB bf16
                    + (size_t)G * (16384ull * 4) * 2        // cnt+sum: G*128KB
                    + (size_t)G * (16384ull * 2)            // pm: G*32KB
                    + 1024;
        if (need <= ws_size) break;
        G >>= 1;
    }

    char* ws = (char*)d_ws;
    size_t off = 0;
    auto carve = [&](size_t bytes) { char* p = ws + off; off += (bytes + 255) & ~255ull; return p; };
    unsigned short* W2  = (unsigned short*)carve(W2_BYTES);
    unsigned short* xT  = (unsigned short*)carve((size_t)G * 16384 * 128 * 2);
    float*          cnt = (float*)carve((size_t)G * 16384 * 4);
    float*          sum = (float*)carve((size_t)G * 16384 * 4);
    unsigned short* pm  = (unsigned short*)carve((size_t)G * 16384 * 2);

    k_w2<<<dim3(1152), dim3(256), 0, stream>>>(krn, W2);
    for (int b0 = 0; b0 < 16; b0 += G) {
        k_transpose_stats<<<dim3(G * 128), dim3(128), 0, stream>>>(x, xT, cnt, sum, b0);
        k_patchmean<<<dim3(G * 64), dim3(256), 0, stream>>>(cnt, sum, pm);
        k_gemm<<<dim3(G * 256), dim3(256), 0, stream>>>(xT, pm, W2, bias, out, b0);
    }
}